// Round 1
// baseline (117.527 us; speedup 1.0000x reference)
//
#include <hip/hip_runtime.h>

#define NT 256

constexpr int LPAD = 8;
constexpr int L0 = 8192;
constexpr int N1 = 4099;   // (8192+7)>>1
constexpr int N2 = 2053;   // (4099+7)>>1
constexpr int N3 = 1030;   // (2053+7)>>1
constexpr int N4 = 518;    // (1030+7)>>1
constexpr int ROW_OUT = N4 + N4 + N3 + N2 + N1;  // 8218

// lo[i] = sum_j GLO[j] * xsym(2i-6+j)   (GLO = pywt db4 rec_lo = dec_lo reversed)
constexpr float GLO[8] = {
    0.23037781330885523f,  0.7148465705525415f,   0.6308807679295904f,
   -0.02798376941698385f, -0.18703481171888114f,  0.030841381835986965f,
    0.032883011666982945f, -0.010597401784997278f };
// hi[i] = sum_j GHI[j] * xsym(2i-6+j)   (GHI[j] = (-1)^j * rec_lo[7-j] = dec_hi reversed)
constexpr float GHI[8] = {
   -0.010597401784997278f, -0.032883011666982945f, 0.030841381835986965f,
    0.18703481171888114f,  -0.02798376941698385f,  -0.6308807679295904f,
    0.7148465705525415f,   -0.23037781330885523f };

// in: padded LDS buffer, xsym(q) = in[LPAD+q]. Writes nout lo's and nout hi's.
__device__ __forceinline__ void dwt_level_lds(const float* __restrict__ in, int nout,
                                              float* __restrict__ lo_out,
                                              float* __restrict__ hi_out, int tid)
{
    for (int i = tid; i < nout; i += NT) {
        const float* p = in + 2 * i + 2;   // LPAD + 2i - 6
        float lo = 0.f, hi = 0.f;
#pragma unroll
        for (int j = 0; j < 8; ++j) {
            float v = p[j];
            lo = fmaf(GLO[j], v, lo);
            hi = fmaf(GHI[j], v, hi);
        }
        lo_out[i] = lo;
        hi_out[i] = hi;
    }
}

__global__ __launch_bounds__(NT) void wavedec4_db4(const float* __restrict__ x,
                                                   float* __restrict__ out)
{
    __shared__ float bufA[LPAD + L0 + 8];   // level inputs with symmetric pads
    __shared__ float bufB[LPAD + N1 + 8];
    const int tid = threadIdx.x;
    const size_t row = blockIdx.x;
    const float* __restrict__ xr = x + row * (size_t)L0;
    float* __restrict__ outr = out + row * (size_t)ROW_OUT;

    // Stage row into bufA interior (16B-aligned LDS vec4 stores at offset LPAD=8)
    const float4* x4 = (const float4*)xr;
    float4* a4 = (float4*)(bufA + LPAD);
    for (int i = tid; i < L0 / 4; i += NT) a4[i] = x4[i];
    if (tid < 7) {
        bufA[LPAD - 1 - tid] = xr[tid];            // xsym(-1-t) = x[t]
        bufA[LPAD + L0 + tid] = xr[L0 - 1 - tid];  // xsym(n+t)  = x[n-1-t]
    }
    __syncthreads();

    // L1: bufA(8192) -> cA1 in bufB, cD1 -> out[4119..]
    dwt_level_lds(bufA, N1, bufB + LPAD, outr + (N4 + N4 + N3 + N2), tid);
    __syncthreads();
    if (tid < 7) {
        bufB[LPAD - 1 - tid] = bufB[LPAD + tid];
        bufB[LPAD + N1 + tid] = bufB[LPAD + N1 - 1 - tid];
    }
    __syncthreads();

    // L2: bufB(4099) -> cA2 in bufA, cD2 -> out[2066..]
    dwt_level_lds(bufB, N2, bufA + LPAD, outr + (N4 + N4 + N3), tid);
    __syncthreads();
    if (tid < 7) {
        bufA[LPAD - 1 - tid] = bufA[LPAD + tid];
        bufA[LPAD + N2 + tid] = bufA[LPAD + N2 - 1 - tid];
    }
    __syncthreads();

    // L3: bufA(2053) -> cA3 in bufB, cD3 -> out[1036..]
    dwt_level_lds(bufA, N3, bufB + LPAD, outr + (N4 + N4), tid);
    __syncthreads();
    if (tid < 7) {
        bufB[LPAD - 1 - tid] = bufB[LPAD + tid];
        bufB[LPAD + N3 + tid] = bufB[LPAD + N3 - 1 - tid];
    }
    __syncthreads();

    // L4: bufB(1030) -> cA4 -> out[0..518), cD4 -> out[518..1036)
    dwt_level_lds(bufB, N4, outr, outr + N4, tid);
}

extern "C" void kernel_launch(void* const* d_in, const int* in_sizes, int n_in,
                              void* d_out, int out_size, void* d_ws, size_t ws_size,
                              hipStream_t stream) {
    const float* x = (const float*)d_in[0];
    float* out = (float*)d_out;
    const int rows = in_sizes[0] / L0;  // 64*32 = 2048
    wavedec4_db4<<<dim3(rows), dim3(NT), 0, stream>>>(x, out);
}